// Round 11
// baseline (154.883 us; speedup 1.0000x reference)
//
#include <hip/hip_runtime.h>

#define NN 50000
#define NE 640000
#define NBK 196      // buckets of 256 nodes
#define CHUNK 2560   // edges per block in bucket passes: NE/CHUNK = 250
#define NXBLK 3125   // X-split blocks: (NN*128/8)/256
#define NWBLK 96     // wprep blocks

typedef __attribute__((ext_vector_type(8))) short s8v;
typedef __attribute__((ext_vector_type(4))) float f4v;

__device__ __forceinline__ unsigned short f2bf(float x) {  // RNE f32->bf16
  unsigned int u = __float_as_uint(x);
  return (unsigned short)((u + 0x7fffu + ((u >> 16) & 1u)) >> 16);
}
__device__ __forceinline__ float bfval(unsigned short h) {
  return __uint_as_float((unsigned int)h << 16);
}
__device__ __forceinline__ float2 bfpair(unsigned int u) {
  float2 r;
  r.x = __uint_as_float((u & 0xffffu) << 16);
  r.y = __uint_as_float(u & 0xffff0000u);
  return r;
}

// ---------------- prep: X hi/lo split + W transpose/split + bcnt|bfill zero ----------------

__global__ __launch_bounds__(256) void prep_kernel(
    const float* __restrict__ x, const float* __restrict__ W1, const float* __restrict__ W2,
    unsigned short* __restrict__ Xh, unsigned short* __restrict__ Xl,
    unsigned short* __restrict__ wt1h, unsigned short* __restrict__ wt1l,
    unsigned short* __restrict__ wt2h, unsigned short* __restrict__ wt2l,
    int* __restrict__ bcnt) {
  const int b = blockIdx.x;
  const int t = threadIdx.x;
  if (b < NXBLK) {
    const int i = b * 256 + t;  // chunk of 8 floats
    float4 v0 = *reinterpret_cast<const float4*>(&x[(size_t)i * 8]);
    float4 v1 = *reinterpret_cast<const float4*>(&x[(size_t)i * 8 + 4]);
    float f[8] = {v0.x, v0.y, v0.z, v0.w, v1.x, v1.y, v1.z, v1.w};
    unsigned int hw[4], lw[4];
#pragma unroll
    for (int j = 0; j < 4; ++j) {
      unsigned short h0 = f2bf(f[2 * j]), h1 = f2bf(f[2 * j + 1]);
      unsigned short l0 = f2bf(f[2 * j] - bfval(h0)), l1 = f2bf(f[2 * j + 1] - bfval(h1));
      hw[j] = (unsigned int)h0 | ((unsigned int)h1 << 16);
      lw[j] = (unsigned int)l0 | ((unsigned int)l1 << 16);
    }
    *reinterpret_cast<uint4*>(&Xh[(size_t)i * 8]) = make_uint4(hw[0], hw[1], hw[2], hw[3]);
    *reinterpret_cast<uint4*>(&Xl[(size_t)i * 8]) = make_uint4(lw[0], lw[1], lw[2], lw[3]);
  } else if (b < NXBLK + NWBLK) {
    int idx = (b - NXBLK) * 256 + t;  // 0..24575
    if (idx < 16384) {
      int c = idx >> 7, k = idx & 127;
      float w = W1[k * 128 + c];
      unsigned short h = f2bf(w);
      wt1h[idx] = h;
      wt1l[idx] = f2bf(w - bfval(h));
    } else {
      int i2 = idx - 16384;
      int c = i2 >> 7, k = i2 & 127;
      float w = W2[k * 64 + c];
      unsigned short h = f2bf(w);
      wt2h[i2] = h;
      wt2l[i2] = f2bf(w - bfval(h));
    }
  } else {
    // BUGFIX (R10 crash): zero ALL 2*NBK=392 ints, not just the first 256.
    for (int i = t; i < 2 * NBK; i += 256) bcnt[i] = 0;  // bcnt | bfill
  }
}

// ---------------- Bucketed CSR (dest-keyed) build ----------------

__global__ __launch_bounds__(256) void bucket_count_kernel(const int* __restrict__ col,
                                                           int* __restrict__ bcnt) {
  __shared__ int h[NBK];
  const int tid = threadIdx.x;
  for (int i = tid; i < NBK; i += 256) h[i] = 0;
  __syncthreads();
  const int base = blockIdx.x * CHUNK;
  for (int i = tid; i < CHUNK; i += 256) atomicAdd(&h[col[base + i] >> 8], 1);
  __syncthreads();
  for (int i = tid; i < NBK; i += 256)
    if (h[i]) atomicAdd(&bcnt[i], h[i]);
}

__global__ __launch_bounds__(256) void scan196_kernel(const int* __restrict__ bcnt,
                                                      int* __restrict__ boff) {
  __shared__ int s[256];
  const int tid = threadIdx.x;
  int v = (tid < NBK) ? bcnt[tid] : 0;
  s[tid] = v;
  __syncthreads();
  for (int off = 1; off < 256; off <<= 1) {
    int u = (tid >= off) ? s[tid - off] : 0;
    __syncthreads();
    s[tid] += u;
    __syncthreads();
  }
  if (tid <= NBK) boff[tid] = (tid == 0) ? 0 : s[tid - 1];
}

__global__ __launch_bounds__(256) void bucket_scatter_kernel(
    const int* __restrict__ row, const int* __restrict__ col,
    const int* __restrict__ boff, int* __restrict__ bfill,
    unsigned int* __restrict__ ebuf) {
  __shared__ int h[NBK], gst[NBK], h2[NBK];
  const int tid = threadIdx.x;
  for (int i = tid; i < NBK; i += 256) { h[i] = 0; h2[i] = 0; }
  __syncthreads();
  const int base = blockIdx.x * CHUNK;
  for (int i = tid; i < CHUNK; i += 256) atomicAdd(&h[col[base + i] >> 8], 1);
  __syncthreads();
  for (int i = tid; i < NBK; i += 256) gst[i] = h[i] ? atomicAdd(&bfill[i], h[i]) : 0;
  __syncthreads();
  for (int i = tid; i < CHUNK; i += 256) {
    int c = col[base + i];
    int b = c >> 8;
    int r = atomicAdd(&h2[b], 1);
    unsigned int packed = ((unsigned int)row[base + i] << 8) | (unsigned int)(c & 255);
    ebuf[boff[b] + gst[b] + r] = packed;
  }
}

__global__ __launch_bounds__(256) void bucket_build_kernel(
    const unsigned int* __restrict__ ebuf, const int* __restrict__ boff,
    int* __restrict__ row_ptr, float* __restrict__ dis, int* __restrict__ csr, int n) {
  __shared__ int cnt[256], c2[256], lbase[256], wsum[4];
  const int tid = threadIdx.x;
  const int b = blockIdx.x;
  const int s0 = boff[b], s1 = boff[b + 1];
  cnt[tid] = 0;
  c2[tid] = 0;
  __syncthreads();
  for (int i = s0 + tid; i < s1; i += 256) atomicAdd(&cnt[ebuf[i] & 255], 1);
  __syncthreads();

  const int lane = tid & 63, w = tid >> 6;
  int c = cnt[tid];
  int inc = c;
#pragma unroll
  for (int off = 1; off < 64; off <<= 1) {
    int u = __shfl_up(inc, off);
    if (lane >= off) inc += u;
  }
  if (lane == 63) wsum[w] = inc;
  __syncthreads();
  int wo = 0;
  for (int i = 0; i < w; ++i) wo += wsum[i];
  const int excl = wo + inc - c;

  const int node = b * 256 + tid;
  if (node <= n) row_ptr[node] = s0 + excl;
  if (node < n) dis[node] = rsqrtf((float)(c + 1));
  lbase[tid] = s0 + excl;
  __syncthreads();

  for (int i = s0 + tid; i < s1; i += 256) {
    unsigned int p = ebuf[i];
    int dl = p & 255;
    int r = atomicAdd(&c2[dl], 1);
    csr[lbase[dl] + r] = (int)(p >> 8);
  }
}

// ---------------- MFMA GEMM: dbuf LDS, ONE barrier per kt ----------------
// out[r][c] = dis[r] * sum_{k<128} A[r][k] * Wt[c][k]
// Pipeline per kt: ds_write(tile kt from prefetch regs) -> issue loads(kt+1)
// -> barrier -> compute(tile kt). Single barrier is safe: __syncthreads drains
// lgkmcnt, so buf's readers (compute kt-2) finish before barrier(kt-1); buf's
// writers (write_tile kt) run after barrier(kt-1).

template <int NCOLS, bool SPLITA, bool OUTBF16>
__global__ __launch_bounds__(256) void gemm_mfma_kernel(
    const unsigned short* __restrict__ Ah_g, const unsigned short* __restrict__ Al_g,
    const unsigned short* __restrict__ Bth, const unsigned short* __restrict__ Btl,
    const float* __restrict__ dis, void* __restrict__ outv, int M) {
  constexpr int WCOL = NCOLS / 64;
  constexpr int WROW = 4 / WCOL;
  constexpr int BM = WROW * 32;          // 64 (gemm1) or 128 (gemm2)
  constexpr int P = 40;                  // LDS pitch
  constexpr int ACH = BM * 4 * (SPLITA ? 2 : 1);   // A 16B-chunks per tile
  constexpr int NCH = (ACH + NCOLS * 8) / 256;     // chunks per thread (6 or 4)

  __shared__ __align__(16) unsigned short Ah[2][BM][P];
  __shared__ __align__(16) unsigned short Al[2][SPLITA ? BM : 1][SPLITA ? P : 1];
  __shared__ __align__(16) unsigned short Bh[2][NCOLS][P];
  __shared__ __align__(16) unsigned short Bl[2][NCOLS][P];

  const int t = threadIdx.x;
  const int lane = t & 63;
  const int l15 = lane & 15;
  const int lg = lane >> 4;
  const int wv = t >> 6;
  const int wr = wv % WROW;
  const int wc = wv / WROW;
  const int rb = blockIdx.x * BM;

  int4 pf[NCH];

  auto issue_loads = [&](int kt) {
#pragma unroll
    for (int j = 0; j < NCH; ++j) {
      int c = t + j * 256;
      const unsigned short* src;
      if (c < BM * 4) {
        int r = c >> 2, kq = c & 3;
        int rr = min(rb + r, M - 1);
        src = &Ah_g[(size_t)rr * 128 + kt * 32 + kq * 8];
      } else if (SPLITA && c < ACH) {
        int cc = c - BM * 4;
        int r = cc >> 2, kq = cc & 3;
        int rr = min(rb + r, M - 1);
        src = &Al_g[(size_t)rr * 128 + kt * 32 + kq * 8];
      } else {
        int i = c - ACH;
        const unsigned short* base = Bth;
        if (i >= NCOLS * 4) { i -= NCOLS * 4; base = Btl; }
        int col = i >> 2, kq = i & 3;
        src = &base[col * 128 + kt * 32 + kq * 8];
      }
      pf[j] = *reinterpret_cast<const int4*>(src);
    }
  };

  auto write_tile = [&](int buf) {
#pragma unroll
    for (int j = 0; j < NCH; ++j) {
      int c = t + j * 256;
      unsigned short* dst;
      if (c < BM * 4) {
        dst = &Ah[buf][c >> 2][(c & 3) * 8];
      } else if (SPLITA && c < ACH) {
        int cc = c - BM * 4;
        dst = &Al[buf][cc >> 2][(cc & 3) * 8];
      } else {
        int i = c - ACH;
        if (i < NCOLS * 4) dst = &Bh[buf][i >> 2][(i & 3) * 8];
        else { i -= NCOLS * 4; dst = &Bl[buf][i >> 2][(i & 3) * 8]; }
      }
      *reinterpret_cast<int4*>(dst) = pf[j];
    }
  };

  f4v acc[2][4];
#pragma unroll
  for (int i = 0; i < 2; ++i)
#pragma unroll
    for (int j = 0; j < 4; ++j) acc[i][j] = (f4v){0.f, 0.f, 0.f, 0.f};

  issue_loads(0);
#pragma unroll
  for (int kt = 0; kt < 4; ++kt) {
    const int buf = kt & 1;
    write_tile(buf);
    if (kt < 3) issue_loads(kt + 1);
    __syncthreads();

    s8v ah[2], al[2];
#pragma unroll
    for (int rg = 0; rg < 2; ++rg) {
      ah[rg] = *reinterpret_cast<const s8v*>(&Ah[buf][wr * 32 + rg * 16 + l15][lg * 8]);
      if constexpr (SPLITA)
        al[rg] = *reinterpret_cast<const s8v*>(&Al[buf][wr * 32 + rg * 16 + l15][lg * 8]);
    }
#pragma unroll
    for (int cg = 0; cg < 4; ++cg) {
      s8v bh = *reinterpret_cast<const s8v*>(&Bh[buf][wc * 64 + cg * 16 + l15][lg * 8]);
      s8v bl = *reinterpret_cast<const s8v*>(&Bl[buf][wc * 64 + cg * 16 + l15][lg * 8]);
#pragma unroll
      for (int rg = 0; rg < 2; ++rg) {
        acc[rg][cg] = __builtin_amdgcn_mfma_f32_16x16x32_bf16(ah[rg], bh, acc[rg][cg], 0, 0, 0);
        acc[rg][cg] = __builtin_amdgcn_mfma_f32_16x16x32_bf16(ah[rg], bl, acc[rg][cg], 0, 0, 0);
        if constexpr (SPLITA)
          acc[rg][cg] = __builtin_amdgcn_mfma_f32_16x16x32_bf16(al[rg], bh, acc[rg][cg], 0, 0, 0);
      }
    }
  }

  // epilogue: scale by dis, store. C/D: col=l15, row_in_16 = lg*4 + g.
  float dv[2][4];
#pragma unroll
  for (int rg = 0; rg < 2; ++rg)
#pragma unroll
    for (int g = 0; g < 4; ++g) {
      int r = rb + wr * 32 + rg * 16 + lg * 4 + g;
      dv[rg][g] = (r < M) ? dis[r] : 0.f;
    }
#pragma unroll
  for (int rg = 0; rg < 2; ++rg)
#pragma unroll
    for (int cg = 0; cg < 4; ++cg) {
      int colc = wc * 64 + cg * 16 + l15;
#pragma unroll
      for (int g = 0; g < 4; ++g) {
        int r = rb + wr * 32 + rg * 16 + lg * 4 + g;
        if (r < M) {
          float o = acc[rg][cg][g] * dv[rg][g];
          if constexpr (OUTBF16)
            ((unsigned short*)outv)[(size_t)r * NCOLS + colc] = f2bf(o);
          else
            ((float*)outv)[(size_t)r * NCOLS + colc] = o;
        }
      }
    }
}

// ---------------- Aggregation (unroll 8, independent accumulators) ----------------

__global__ __launch_bounds__(256) void agg_bf16_kernel(
    const unsigned int* __restrict__ H, const int* __restrict__ row_ptr,
    const int* __restrict__ csr, const float* __restrict__ dis,
    const float* __restrict__ bias, unsigned int* __restrict__ Z, int n) {
  const int lane = threadIdx.x & 63;
  const int node = blockIdx.x * 4 + (threadIdx.x >> 6);
  if (node >= n) return;

  float2 a[8];
  a[0] = bfpair(H[(size_t)node * 64 + lane]);  // self-loop
#pragma unroll
  for (int i = 1; i < 8; ++i) a[i] = make_float2(0.f, 0.f);

  const int s0 = row_ptr[node], s1 = row_ptr[node + 1];
  for (int e = s0; e < s1; e += 64) {
    int m = s1 - e;
    if (m > 64) m = 64;
    int idx = 0;
    if (lane < m) idx = csr[e + lane];
    int j = 0;
    for (; j + 8 <= m; j += 8) {
      int i0 = __shfl(idx, j),     i1 = __shfl(idx, j + 1);
      int i2 = __shfl(idx, j + 2), i3 = __shfl(idx, j + 3);
      int i4 = __shfl(idx, j + 4), i5 = __shfl(idx, j + 5);
      int i6 = __shfl(idx, j + 6), i7 = __shfl(idx, j + 7);
      float2 v0 = bfpair(H[(size_t)i0 * 64 + lane]);
      float2 v1 = bfpair(H[(size_t)i1 * 64 + lane]);
      float2 v2 = bfpair(H[(size_t)i2 * 64 + lane]);
      float2 v3 = bfpair(H[(size_t)i3 * 64 + lane]);
      float2 v4 = bfpair(H[(size_t)i4 * 64 + lane]);
      float2 v5 = bfpair(H[(size_t)i5 * 64 + lane]);
      float2 v6 = bfpair(H[(size_t)i6 * 64 + lane]);
      float2 v7 = bfpair(H[(size_t)i7 * 64 + lane]);
      a[0].x += v0.x; a[0].y += v0.y;  a[1].x += v1.x; a[1].y += v1.y;
      a[2].x += v2.x; a[2].y += v2.y;  a[3].x += v3.x; a[3].y += v3.y;
      a[4].x += v4.x; a[4].y += v4.y;  a[5].x += v5.x; a[5].y += v5.y;
      a[6].x += v6.x; a[6].y += v6.y;  a[7].x += v7.x; a[7].y += v7.y;
    }
    for (; j + 4 <= m; j += 4) {
      int i0 = __shfl(idx, j),     i1 = __shfl(idx, j + 1);
      int i2 = __shfl(idx, j + 2), i3 = __shfl(idx, j + 3);
      float2 v0 = bfpair(H[(size_t)i0 * 64 + lane]);
      float2 v1 = bfpair(H[(size_t)i1 * 64 + lane]);
      float2 v2 = bfpair(H[(size_t)i2 * 64 + lane]);
      float2 v3 = bfpair(H[(size_t)i3 * 64 + lane]);
      a[0].x += v0.x; a[0].y += v0.y;  a[1].x += v1.x; a[1].y += v1.y;
      a[2].x += v2.x; a[2].y += v2.y;  a[3].x += v3.x; a[3].y += v3.y;
    }
    for (; j < m; ++j) {
      float2 v = bfpair(H[(size_t)__shfl(idx, j) * 64 + lane]);
      a[0].x += v.x; a[0].y += v.y;
    }
  }
  const float d = dis[node];
  float2 b = *reinterpret_cast<const float2*>(&bias[lane * 2]);
  float sx = ((a[0].x + a[1].x) + (a[2].x + a[3].x)) + ((a[4].x + a[5].x) + (a[6].x + a[7].x));
  float sy = ((a[0].y + a[1].y) + (a[2].y + a[3].y)) + ((a[4].y + a[5].y) + (a[6].y + a[7].y));
  float ox = fmaxf(sx * d + b.x, 0.f);
  float oy = fmaxf(sy * d + b.y, 0.f);
  Z[(size_t)node * 64 + lane] = (unsigned int)f2bf(ox) | ((unsigned int)f2bf(oy) << 16);
}

__global__ __launch_bounds__(256) void agg_f32_kernel(
    const float* __restrict__ Hs, const int* __restrict__ row_ptr,
    const int* __restrict__ csr, const float* __restrict__ dis,
    const float* __restrict__ bias, float* __restrict__ out, int n) {
  const int lane = threadIdx.x & 63;
  const int node = blockIdx.x * 4 + (threadIdx.x >> 6);
  if (node >= n) return;

  float a[8];
  a[0] = Hs[(size_t)node * 64 + lane];  // self-loop
#pragma unroll
  for (int i = 1; i < 8; ++i) a[i] = 0.f;

  const int s0 = row_ptr[node], s1 = row_ptr[node + 1];
  for (int e = s0; e < s1; e += 64) {
    int m = s1 - e;
    if (m > 64) m = 64;
    int idx = 0;
    if (lane < m) idx = csr[e + lane];
    int j = 0;
    for (; j + 8 <= m; j += 8) {
      int i0 = __shfl(idx, j),     i1 = __shfl(idx, j + 1);
      int i2 = __shfl(idx, j + 2), i3 = __shfl(idx, j + 3);
      int i4 = __shfl(idx, j + 4), i5 = __shfl(idx, j + 5);
      int i6 = __shfl(idx, j + 6), i7 = __shfl(idx, j + 7);
      float v0 = Hs[(size_t)i0 * 64 + lane];
      float v1 = Hs[(size_t)i1 * 64 + lane];
      float v2 = Hs[(size_t)i2 * 64 + lane];
      float v3 = Hs[(size_t)i3 * 64 + lane];
      float v4 = Hs[(size_t)i4 * 64 + lane];
      float v5 = Hs[(size_t)i5 * 64 + lane];
      float v6 = Hs[(size_t)i6 * 64 + lane];
      float v7 = Hs[(size_t)i7 * 64 + lane];
      a[0] += v0; a[1] += v1; a[2] += v2; a[3] += v3;
      a[4] += v4; a[5] += v5; a[6] += v6; a[7] += v7;
    }
    for (; j + 4 <= m; j += 4) {
      int i0 = __shfl(idx, j),     i1 = __shfl(idx, j + 1);
      int i2 = __shfl(idx, j + 2), i3 = __shfl(idx, j + 3);
      float v0 = Hs[(size_t)i0 * 64 + lane];
      float v1 = Hs[(size_t)i1 * 64 + lane];
      float v2 = Hs[(size_t)i2 * 64 + lane];
      float v3 = Hs[(size_t)i3 * 64 + lane];
      a[0] += v0; a[1] += v1; a[2] += v2; a[3] += v3;
    }
    for (; j < m; ++j) a[0] += Hs[(size_t)__shfl(idx, j) * 64 + lane];
  }
  float s = ((a[0] + a[1]) + (a[2] + a[3])) + ((a[4] + a[5]) + (a[6] + a[7]));
  out[(size_t)node * 64 + lane] = s * dis[node] + bias[lane];
}

// ---------------- launch ----------------

extern "C" void kernel_launch(void* const* d_in, const int* in_sizes, int n_in,
                              void* d_out, int out_size, void* d_ws, size_t ws_size,
                              hipStream_t stream) {
  const float* x  = (const float*)d_in[0];
  const int*   ei = (const int*)d_in[1];
  const float* W1 = (const float*)d_in[2];
  const float* b1 = (const float*)d_in[3];
  const float* W2 = (const float*)d_in[4];
  const float* b2 = (const float*)d_in[5];
  float* out = (float*)d_out;

  const int* row = ei;        // source nodes
  const int* col = ei + NE;   // destination nodes

  char* ws = (char*)d_ws;
  size_t off = 0;
  auto alloc = [&](size_t bytes) -> void* {
    off = (off + 255) & ~(size_t)255;
    void* p = ws + off;
    off += bytes;
    return p;
  };

  int* bcnt    = (int*)alloc((size_t)2 * NBK * sizeof(int));  // bcnt | bfill
  int* bfill   = bcnt + NBK;
  int* boff    = (int*)alloc((size_t)(NBK + 1) * sizeof(int));
  unsigned int* ebuf = (unsigned int*)alloc((size_t)NE * sizeof(unsigned int));
  int* row_ptr = (int*)alloc((size_t)(NN + 1) * sizeof(int));
  int* csr     = (int*)alloc((size_t)NE * sizeof(int));
  float* dis   = (float*)alloc((size_t)NN * sizeof(float));
  unsigned short* wt1h = (unsigned short*)alloc((size_t)(2 * 128 * 128 + 2 * 64 * 128) * 2);
  unsigned short* wt1l = wt1h + 128 * 128;
  unsigned short* wt2h = wt1l + 128 * 128;
  unsigned short* wt2l = wt2h + 64 * 128;
  unsigned short* Xh = (unsigned short*)alloc((size_t)NN * 128 * 2);
  unsigned short* Xl = (unsigned short*)alloc((size_t)NN * 128 * 2);
  // HT region: bf16 [NN][128] for layer-1 GEMM out, then f32 [NN][64] for layer-2
  unsigned short* HT16 = (unsigned short*)alloc((size_t)NN * 128 * 2);
  float* HT32 = (float*)HT16;
  unsigned int* HTu = (unsigned int*)HT16;
  unsigned short* Z1 = (unsigned short*)alloc((size_t)NN * 128 * 2);
  unsigned int* Z1u = (unsigned int*)Z1;

  prep_kernel<<<NXBLK + NWBLK + 1, 256, 0, stream>>>(x, W1, W2, Xh, Xl,
                                                     wt1h, wt1l, wt2h, wt2l, bcnt);
  bucket_count_kernel<<<NE / CHUNK, 256, 0, stream>>>(col, bcnt);
  scan196_kernel<<<1, 256, 0, stream>>>(bcnt, boff);
  bucket_scatter_kernel<<<NE / CHUNK, 256, 0, stream>>>(row, col, boff, bfill, ebuf);
  bucket_build_kernel<<<NBK, 256, 0, stream>>>(ebuf, boff, row_ptr, dis, csr, NN);

  const int ga = (NN + 3) / 4;

  // Layer 1: HT16 = bf16( dis .* (X @ W1) )  [NN][128]
  gemm_mfma_kernel<128, true, true><<<(NN + 63) / 64, 256, 0, stream>>>(
      Xh, Xl, wt1h, wt1l, dis, HT16, NN);
  agg_bf16_kernel<<<ga, 256, 0, stream>>>(HTu, row_ptr, csr, dis, b1, Z1u, NN);

  // Layer 2: HT32 = dis .* (Z1 @ W2)  [NN][64]
  gemm_mfma_kernel<64, false, false><<<(NN + 127) / 128, 256, 0, stream>>>(
      Z1, nullptr, wt2h, wt2l, dis, HT32, NN);
  agg_f32_kernel<<<ga, 256, 0, stream>>>(HT32, row_ptr, csr, dis, b2, out, NN);
}

// Round 12
// 132.499 us; speedup vs baseline: 1.1689x; 1.1689x over previous
//
#include <hip/hip_runtime.h>

#define NN 50000
#define NE 640000
#define NBK 196      // buckets of 256 nodes
#define CHUNK 2560   // edges per block in bucket passes: NE/CHUNK = 250

typedef __attribute__((ext_vector_type(8))) short s8v;
typedef __attribute__((ext_vector_type(4))) float f4v;

__device__ __forceinline__ unsigned short f2bf(float x) {  // RNE f32->bf16
  unsigned int u = __float_as_uint(x);
  return (unsigned short)((u + 0x7fffu + ((u >> 16) & 1u)) >> 16);
}
__device__ __forceinline__ float bfval(unsigned short h) {
  return __uint_as_float((unsigned int)h << 16);
}
__device__ __forceinline__ float2 bfpair(unsigned int u) {
  float2 r;
  r.x = __uint_as_float((u & 0xffffu) << 16);
  r.y = __uint_as_float(u & 0xffff0000u);
  return r;
}

// ---------------- Bucketed CSR (dest-keyed) build ----------------

__global__ __launch_bounds__(256) void bucket_count_kernel(const int* __restrict__ col,
                                                           int* __restrict__ bcnt) {
  __shared__ int h[NBK];
  const int tid = threadIdx.x;
  for (int i = tid; i < NBK; i += 256) h[i] = 0;
  __syncthreads();
  const int base = blockIdx.x * CHUNK;
  for (int i = tid; i < CHUNK; i += 256) atomicAdd(&h[col[base + i] >> 8], 1);
  __syncthreads();
  for (int i = tid; i < NBK; i += 256)
    if (h[i]) atomicAdd(&bcnt[i], h[i]);
}

__global__ __launch_bounds__(256) void scan196_kernel(const int* __restrict__ bcnt,
                                                      int* __restrict__ boff) {
  __shared__ int s[256];
  const int tid = threadIdx.x;
  int v = (tid < NBK) ? bcnt[tid] : 0;
  s[tid] = v;
  __syncthreads();
  for (int off = 1; off < 256; off <<= 1) {
    int u = (tid >= off) ? s[tid - off] : 0;
    __syncthreads();
    s[tid] += u;
    __syncthreads();
  }
  if (tid <= NBK) boff[tid] = (tid == 0) ? 0 : s[tid - 1];
}

__global__ __launch_bounds__(256) void bucket_scatter_kernel(
    const int* __restrict__ row, const int* __restrict__ col,
    const int* __restrict__ boff, int* __restrict__ bfill,
    unsigned int* __restrict__ ebuf) {
  __shared__ int h[NBK], gst[NBK], h2[NBK];
  const int tid = threadIdx.x;
  for (int i = tid; i < NBK; i += 256) { h[i] = 0; h2[i] = 0; }
  __syncthreads();
  const int base = blockIdx.x * CHUNK;
  for (int i = tid; i < CHUNK; i += 256) atomicAdd(&h[col[base + i] >> 8], 1);
  __syncthreads();
  for (int i = tid; i < NBK; i += 256) gst[i] = h[i] ? atomicAdd(&bfill[i], h[i]) : 0;
  __syncthreads();
  for (int i = tid; i < CHUNK; i += 256) {
    int c = col[base + i];
    int b = c >> 8;
    int r = atomicAdd(&h2[b], 1);
    unsigned int packed = ((unsigned int)row[base + i] << 8) | (unsigned int)(c & 255);
    ebuf[boff[b] + gst[b] + r] = packed;
  }
}

__global__ __launch_bounds__(256) void bucket_build_kernel(
    const unsigned int* __restrict__ ebuf, const int* __restrict__ boff,
    int* __restrict__ row_ptr, float* __restrict__ dis, int* __restrict__ csr, int n) {
  __shared__ int cnt[256], c2[256], lbase[256], wsum[4];
  const int tid = threadIdx.x;
  const int b = blockIdx.x;
  const int s0 = boff[b], s1 = boff[b + 1];
  cnt[tid] = 0;
  c2[tid] = 0;
  __syncthreads();
  for (int i = s0 + tid; i < s1; i += 256) atomicAdd(&cnt[ebuf[i] & 255], 1);
  __syncthreads();

  const int lane = tid & 63, w = tid >> 6;
  int c = cnt[tid];
  int inc = c;
#pragma unroll
  for (int off = 1; off < 64; off <<= 1) {
    int u = __shfl_up(inc, off);
    if (lane >= off) inc += u;
  }
  if (lane == 63) wsum[w] = inc;
  __syncthreads();
  int wo = 0;
  for (int i = 0; i < w; ++i) wo += wsum[i];
  const int excl = wo + inc - c;

  const int node = b * 256 + tid;
  if (node <= n) row_ptr[node] = s0 + excl;
  if (node < n) dis[node] = rsqrtf((float)(c + 1));
  lbase[tid] = s0 + excl;
  __syncthreads();

  for (int i = s0 + tid; i < s1; i += 256) {
    unsigned int p = ebuf[i];
    int dl = p & 255;
    int r = atomicAdd(&c2[dl], 1);
    csr[lbase[dl] + r] = (int)(p >> 8);
  }
}

// ---------------- W prep: transpose + split f32 -> bf16 hi/lo ----------------

__global__ __launch_bounds__(256) void wprep_kernel(
    const float* __restrict__ W1, const float* __restrict__ W2,
    unsigned short* __restrict__ wt1h, unsigned short* __restrict__ wt1l,
    unsigned short* __restrict__ wt2h, unsigned short* __restrict__ wt2l) {
  int idx = blockIdx.x * 256 + threadIdx.x;  // 0..24575
  if (idx < 16384) {
    int c = idx >> 7, k = idx & 127;
    float w = W1[k * 128 + c];
    unsigned short h = f2bf(w);
    wt1h[idx] = h;
    wt1l[idx] = f2bf(w - bfval(h));
  } else if (idx < 24576) {
    int i2 = idx - 16384;
    int c = i2 >> 7, k = i2 & 127;
    float w = W2[k * 64 + c];
    unsigned short h = f2bf(w);
    wt2h[i2] = h;
    wt2l[i2] = f2bf(w - bfval(h));
  }
}

// ---------------- MFMA GEMM (R5/R9-proven single-buffer 2-barrier template,
//                  generalized wave tile: RG 16-row groups per wave) ----------------
// out[r][c] = dis[r] * sum_{k<128} A[r][k] * Wt[c][k]
// gemm1: BM=128, NCOLS=128 -> 4 waves as 2x2, wave = 64 rows x 64 cols (48 MFMA/kt/wave)
// gemm2: BM=128, NCOLS=64  -> 4 waves as 4x1, wave = 32 rows x 64 cols (R9-identical)

template <int BM, int NCOLS, bool SPLITA, bool OUTBF16>
__global__ __launch_bounds__(256) void gemm_mfma_kernel(
    const void* __restrict__ Av, const unsigned short* __restrict__ Bth,
    const unsigned short* __restrict__ Btl, const float* __restrict__ dis,
    void* __restrict__ outv, int M) {
  constexpr int WCOL = NCOLS / 64;       // waves along cols
  constexpr int WROW = 4 / WCOL;         // waves along rows
  constexpr int RG = BM / (WROW * 16);   // 16-row groups per wave
  constexpr int P = 40;                  // LDS pitch in bf16 (16B-aligned, proven 0-conflict)

  __shared__ unsigned short Ah[BM][P];
  __shared__ unsigned short Al[SPLITA ? BM : 1][SPLITA ? P : 1];
  __shared__ unsigned short Bh[NCOLS][P];
  __shared__ unsigned short Bl[NCOLS][P];

  const int t = threadIdx.x;
  const int lane = t & 63;
  const int l15 = lane & 15;
  const int lg = lane >> 4;
  const int wv = t >> 6;
  const int wr = wv % WROW;
  const int wc = wv / WROW;
  const int rb = blockIdx.x * BM;

  f4v acc[RG][4];
#pragma unroll
  for (int i = 0; i < RG; ++i)
#pragma unroll
    for (int j = 0; j < 4; ++j) acc[i][j] = (f4v){0.f, 0.f, 0.f, 0.f};

  for (int kt = 0; kt < 4; ++kt) {
    if (kt) __syncthreads();
    // stage B tile [NCOLS][32] hi+lo
#pragma unroll
    for (int f = t; f < NCOLS * 4; f += 256) {
      int c = f >> 2, kq = f & 3;
      *reinterpret_cast<int4*>(&Bh[c][kq * 8]) =
          *reinterpret_cast<const int4*>(&Bth[c * 128 + kt * 32 + kq * 8]);
      *reinterpret_cast<int4*>(&Bl[c][kq * 8]) =
          *reinterpret_cast<const int4*>(&Btl[c * 128 + kt * 32 + kq * 8]);
    }
    // stage A tile [BM][32]
    if constexpr (SPLITA) {
      const float* A = (const float*)Av;
#pragma unroll
      for (int j = 0; j < BM * 8 / 256; ++j) {
        int f = t + j * 256;  // BM*8 float4 chunks
        int r = f >> 3, kq = f & 7;
        float4 v = make_float4(0.f, 0.f, 0.f, 0.f);
        if (rb + r < M)
          v = *reinterpret_cast<const float4*>(&A[(size_t)(rb + r) * 128 + kt * 32 + kq * 4]);
        ushort4 hv, lv;
        hv.x = f2bf(v.x); hv.y = f2bf(v.y); hv.z = f2bf(v.z); hv.w = f2bf(v.w);
        lv.x = f2bf(v.x - bfval(hv.x)); lv.y = f2bf(v.y - bfval(hv.y));
        lv.z = f2bf(v.z - bfval(hv.z)); lv.w = f2bf(v.w - bfval(hv.w));
        *reinterpret_cast<ushort4*>(&Ah[r][kq * 4]) = hv;
        *reinterpret_cast<ushort4*>(&Al[r][kq * 4]) = lv;
      }
    } else {
      const unsigned short* A = (const unsigned short*)Av;
#pragma unroll
      for (int j = 0; j < BM * 4 / 256; ++j) {
        int f = t + j * 256;  // BM*4 int4 chunks
        int r = f >> 2, kq = f & 3;
        int4 v = {0, 0, 0, 0};
        if (rb + r < M)
          v = *reinterpret_cast<const int4*>(&A[(size_t)(rb + r) * 128 + kt * 32 + kq * 8]);
        *reinterpret_cast<int4*>(&Ah[r][kq * 8]) = v;
      }
    }
    __syncthreads();

    s8v afh[RG], afl[RG];
#pragma unroll
    for (int rg = 0; rg < RG; ++rg) {
      afh[rg] = *reinterpret_cast<const s8v*>(&Ah[wr * (RG * 16) + rg * 16 + l15][lg * 8]);
      if constexpr (SPLITA)
        afl[rg] = *reinterpret_cast<const s8v*>(&Al[wr * (RG * 16) + rg * 16 + l15][lg * 8]);
    }
#pragma unroll
    for (int cg = 0; cg < 4; ++cg) {
      s8v bh = *reinterpret_cast<const s8v*>(&Bh[wc * 64 + cg * 16 + l15][lg * 8]);
      s8v bl = *reinterpret_cast<const s8v*>(&Bl[wc * 64 + cg * 16 + l15][lg * 8]);
#pragma unroll
      for (int rg = 0; rg < RG; ++rg) {
        acc[rg][cg] = __builtin_amdgcn_mfma_f32_16x16x32_bf16(afh[rg], bh, acc[rg][cg], 0, 0, 0);
        acc[rg][cg] = __builtin_amdgcn_mfma_f32_16x16x32_bf16(afh[rg], bl, acc[rg][cg], 0, 0, 0);
        if constexpr (SPLITA)
          acc[rg][cg] = __builtin_amdgcn_mfma_f32_16x16x32_bf16(afl[rg], bh, acc[rg][cg], 0, 0, 0);
      }
    }
  }

  // epilogue: scale by dis, store. C/D: col=l15, row_in_16 = lg*4 + g.
  float dv[RG][4];
#pragma unroll
  for (int rg = 0; rg < RG; ++rg)
#pragma unroll
    for (int g = 0; g < 4; ++g) {
      int r = rb + wr * (RG * 16) + rg * 16 + lg * 4 + g;
      dv[rg][g] = (r < M) ? dis[r] : 0.f;
    }
#pragma unroll
  for (int rg = 0; rg < RG; ++rg)
#pragma unroll
    for (int cg = 0; cg < 4; ++cg) {
      int colc = wc * 64 + cg * 16 + l15;
#pragma unroll
      for (int g = 0; g < 4; ++g) {
        int r = rb + wr * (RG * 16) + rg * 16 + lg * 4 + g;
        if (r < M) {
          float o = acc[rg][cg][g] * dv[rg][g];
          if constexpr (OUTBF16)
            ((unsigned short*)outv)[(size_t)r * NCOLS + colc] = f2bf(o);
          else
            ((float*)outv)[(size_t)r * NCOLS + colc] = o;
        }
      }
    }
}

// ---------------- Aggregation (unroll 8, independent accumulators) ----------------

__global__ __launch_bounds__(256) void agg_bf16_kernel(
    const unsigned int* __restrict__ H, const int* __restrict__ row_ptr,
    const int* __restrict__ csr, const float* __restrict__ dis,
    const float* __restrict__ bias, unsigned int* __restrict__ Z, int n) {
  const int lane = threadIdx.x & 63;
  const int node = blockIdx.x * 4 + (threadIdx.x >> 6);
  if (node >= n) return;

  float2 a[8];
  a[0] = bfpair(H[(size_t)node * 64 + lane]);  // self-loop
#pragma unroll
  for (int i = 1; i < 8; ++i) a[i] = make_float2(0.f, 0.f);

  const int s0 = row_ptr[node], s1 = row_ptr[node + 1];
  for (int e = s0; e < s1; e += 64) {
    int m = s1 - e;
    if (m > 64) m = 64;
    int idx = 0;
    if (lane < m) idx = csr[e + lane];
    int j = 0;
    for (; j + 8 <= m; j += 8) {
      int i0 = __shfl(idx, j),     i1 = __shfl(idx, j + 1);
      int i2 = __shfl(idx, j + 2), i3 = __shfl(idx, j + 3);
      int i4 = __shfl(idx, j + 4), i5 = __shfl(idx, j + 5);
      int i6 = __shfl(idx, j + 6), i7 = __shfl(idx, j + 7);
      float2 v0 = bfpair(H[(size_t)i0 * 64 + lane]);
      float2 v1 = bfpair(H[(size_t)i1 * 64 + lane]);
      float2 v2 = bfpair(H[(size_t)i2 * 64 + lane]);
      float2 v3 = bfpair(H[(size_t)i3 * 64 + lane]);
      float2 v4 = bfpair(H[(size_t)i4 * 64 + lane]);
      float2 v5 = bfpair(H[(size_t)i5 * 64 + lane]);
      float2 v6 = bfpair(H[(size_t)i6 * 64 + lane]);
      float2 v7 = bfpair(H[(size_t)i7 * 64 + lane]);
      a[0].x += v0.x; a[0].y += v0.y;  a[1].x += v1.x; a[1].y += v1.y;
      a[2].x += v2.x; a[2].y += v2.y;  a[3].x += v3.x; a[3].y += v3.y;
      a[4].x += v4.x; a[4].y += v4.y;  a[5].x += v5.x; a[5].y += v5.y;
      a[6].x += v6.x; a[6].y += v6.y;  a[7].x += v7.x; a[7].y += v7.y;
    }
    for (; j + 4 <= m; j += 4) {
      int i0 = __shfl(idx, j),     i1 = __shfl(idx, j + 1);
      int i2 = __shfl(idx, j + 2), i3 = __shfl(idx, j + 3);
      float2 v0 = bfpair(H[(size_t)i0 * 64 + lane]);
      float2 v1 = bfpair(H[(size_t)i1 * 64 + lane]);
      float2 v2 = bfpair(H[(size_t)i2 * 64 + lane]);
      float2 v3 = bfpair(H[(size_t)i3 * 64 + lane]);
      a[0].x += v0.x; a[0].y += v0.y;  a[1].x += v1.x; a[1].y += v1.y;
      a[2].x += v2.x; a[2].y += v2.y;  a[3].x += v3.x; a[3].y += v3.y;
    }
    for (; j < m; ++j) {
      float2 v = bfpair(H[(size_t)__shfl(idx, j) * 64 + lane]);
      a[0].x += v.x; a[0].y += v.y;
    }
  }
  const float d = dis[node];
  float2 b = *reinterpret_cast<const float2*>(&bias[lane * 2]);
  float sx = ((a[0].x + a[1].x) + (a[2].x + a[3].x)) + ((a[4].x + a[5].x) + (a[6].x + a[7].x));
  float sy = ((a[0].y + a[1].y) + (a[2].y + a[3].y)) + ((a[4].y + a[5].y) + (a[6].y + a[7].y));
  float ox = fmaxf(sx * d + b.x, 0.f);
  float oy = fmaxf(sy * d + b.y, 0.f);
  Z[(size_t)node * 64 + lane] = (unsigned int)f2bf(ox) | ((unsigned int)f2bf(oy) << 16);
}

__global__ __launch_bounds__(256) void agg_f32_kernel(
    const float* __restrict__ Hs, const int* __restrict__ row_ptr,
    const int* __restrict__ csr, const float* __restrict__ dis,
    const float* __restrict__ bias, float* __restrict__ out, int n) {
  const int lane = threadIdx.x & 63;
  const int node = blockIdx.x * 4 + (threadIdx.x >> 6);
  if (node >= n) return;

  float a[8];
  a[0] = Hs[(size_t)node * 64 + lane];  // self-loop
#pragma unroll
  for (int i = 1; i < 8; ++i) a[i] = 0.f;

  const int s0 = row_ptr[node], s1 = row_ptr[node + 1];
  for (int e = s0; e < s1; e += 64) {
    int m = s1 - e;
    if (m > 64) m = 64;
    int idx = 0;
    if (lane < m) idx = csr[e + lane];
    int j = 0;
    for (; j + 8 <= m; j += 8) {
      int i0 = __shfl(idx, j),     i1 = __shfl(idx, j + 1);
      int i2 = __shfl(idx, j + 2), i3 = __shfl(idx, j + 3);
      int i4 = __shfl(idx, j + 4), i5 = __shfl(idx, j + 5);
      int i6 = __shfl(idx, j + 6), i7 = __shfl(idx, j + 7);
      float v0 = Hs[(size_t)i0 * 64 + lane];
      float v1 = Hs[(size_t)i1 * 64 + lane];
      float v2 = Hs[(size_t)i2 * 64 + lane];
      float v3 = Hs[(size_t)i3 * 64 + lane];
      float v4 = Hs[(size_t)i4 * 64 + lane];
      float v5 = Hs[(size_t)i5 * 64 + lane];
      float v6 = Hs[(size_t)i6 * 64 + lane];
      float v7 = Hs[(size_t)i7 * 64 + lane];
      a[0] += v0; a[1] += v1; a[2] += v2; a[3] += v3;
      a[4] += v4; a[5] += v5; a[6] += v6; a[7] += v7;
    }
    for (; j + 4 <= m; j += 4) {
      int i0 = __shfl(idx, j),     i1 = __shfl(idx, j + 1);
      int i2 = __shfl(idx, j + 2), i3 = __shfl(idx, j + 3);
      float v0 = Hs[(size_t)i0 * 64 + lane];
      float v1 = Hs[(size_t)i1 * 64 + lane];
      float v2 = Hs[(size_t)i2 * 64 + lane];
      float v3 = Hs[(size_t)i3 * 64 + lane];
      a[0] += v0; a[1] += v1; a[2] += v2; a[3] += v3;
    }
    for (; j < m; ++j) a[0] += Hs[(size_t)__shfl(idx, j) * 64 + lane];
  }
  float s = ((a[0] + a[1]) + (a[2] + a[3])) + ((a[4] + a[5]) + (a[6] + a[7]));
  out[(size_t)node * 64 + lane] = s * dis[node] + bias[lane];
}

// ---------------- launch ----------------

extern "C" void kernel_launch(void* const* d_in, const int* in_sizes, int n_in,
                              void* d_out, int out_size, void* d_ws, size_t ws_size,
                              hipStream_t stream) {
  const float* x  = (const float*)d_in[0];
  const int*   ei = (const int*)d_in[1];
  const float* W1 = (const float*)d_in[2];
  const float* b1 = (const float*)d_in[3];
  const float* W2 = (const float*)d_in[4];
  const float* b2 = (const float*)d_in[5];
  float* out = (float*)d_out;

  const int* row = ei;        // source nodes
  const int* col = ei + NE;   // destination nodes

  char* ws = (char*)d_ws;
  size_t off = 0;
  auto alloc = [&](size_t bytes) -> void* {
    off = (off + 255) & ~(size_t)255;
    void* p = ws + off;
    off += bytes;
    return p;
  };

  int* bcnt    = (int*)alloc((size_t)2 * NBK * sizeof(int));  // bcnt | bfill
  int* bfill   = bcnt + NBK;
  int* boff    = (int*)alloc((size_t)(NBK + 1) * sizeof(int));
  unsigned int* ebuf = (unsigned int*)alloc((size_t)NE * sizeof(unsigned int));
  int* row_ptr = (int*)alloc((size_t)(NN + 1) * sizeof(int));
  int* csr     = (int*)alloc((size_t)NE * sizeof(int));
  float* dis   = (float*)alloc((size_t)NN * sizeof(float));
  unsigned short* wt1h = (unsigned short*)alloc((size_t)(2 * 128 * 128 + 2 * 64 * 128) * 2);
  unsigned short* wt1l = wt1h + 128 * 128;
  unsigned short* wt2h = wt1l + 128 * 128;
  unsigned short* wt2l = wt2h + 64 * 128;
  // HT region: bf16 [NN][128] for layer-1 GEMM out, then f32 [NN][64] for layer-2
  unsigned short* HT16 = (unsigned short*)alloc((size_t)NN * 128 * 2);
  float* HT32 = (float*)HT16;
  unsigned int* HTu = (unsigned int*)HT16;
  unsigned short* Z1 = (unsigned short*)alloc((size_t)NN * 128 * 2);
  unsigned int* Z1u = (unsigned int*)Z1;

  hipMemsetAsync(bcnt, 0, (size_t)2 * NBK * sizeof(int), stream);
  wprep_kernel<<<96, 256, 0, stream>>>(W1, W2, wt1h, wt1l, wt2h, wt2l);
  bucket_count_kernel<<<NE / CHUNK, 256, 0, stream>>>(col, bcnt);
  scan196_kernel<<<1, 256, 0, stream>>>(bcnt, boff);
  bucket_scatter_kernel<<<NE / CHUNK, 256, 0, stream>>>(row, col, boff, bfill, ebuf);
  bucket_build_kernel<<<NBK, 256, 0, stream>>>(ebuf, boff, row_ptr, dis, csr, NN);

  const int ga = (NN + 3) / 4;
  const int gg = (NN + 127) / 128;  // 391 blocks for BM=128

  // Layer 1: HT16 = bf16( dis .* (X @ W1) )  [NN][128]
  gemm_mfma_kernel<128, 128, true, true><<<gg, 256, 0, stream>>>(
      x, wt1h, wt1l, dis, HT16, NN);
  agg_bf16_kernel<<<ga, 256, 0, stream>>>(HTu, row_ptr, csr, dis, b1, Z1u, NN);

  // Layer 2: HT32 = dis .* (Z1 @ W2)  [NN][64]
  gemm_mfma_kernel<128, 64, false, false><<<gg, 256, 0, stream>>>(
      Z1, wt2h, wt2l, dis, HT32, NN);
  agg_f32_kernel<<<ga, 256, 0, stream>>>(HT32, row_ptr, csr, dis, b2, out, NN);
}

// Round 13
// 125.771 us; speedup vs baseline: 1.2315x; 1.0535x over previous
//
#include <hip/hip_runtime.h>

#define NN 50000
#define NE 640000
#define NBK 196      // buckets of 256 nodes
#define CHUNK 2560   // edges per block in bucket passes: NE/CHUNK = 250

typedef __attribute__((ext_vector_type(8))) short s8v;
typedef __attribute__((ext_vector_type(4))) float f4v;

__device__ __forceinline__ unsigned short f2bf(float x) {  // RNE f32->bf16
  unsigned int u = __float_as_uint(x);
  return (unsigned short)((u + 0x7fffu + ((u >> 16) & 1u)) >> 16);
}
__device__ __forceinline__ float bfval(unsigned short h) {
  return __uint_as_float((unsigned int)h << 16);
}
__device__ __forceinline__ float2 bfpair(unsigned int u) {
  float2 r;
  r.x = __uint_as_float((u & 0xffffu) << 16);
  r.y = __uint_as_float(u & 0xffff0000u);
  return r;
}

// ---------------- Bucketed CSR (dest-keyed) build ----------------

__global__ __launch_bounds__(256) void bucket_count_kernel(const int* __restrict__ col,
                                                           int* __restrict__ bcnt) {
  __shared__ int h[NBK];
  const int tid = threadIdx.x;
  for (int i = tid; i < NBK; i += 256) h[i] = 0;
  __syncthreads();
  const int base = blockIdx.x * CHUNK;
  for (int i = tid; i < CHUNK; i += 256) atomicAdd(&h[col[base + i] >> 8], 1);
  __syncthreads();
  for (int i = tid; i < NBK; i += 256)
    if (h[i]) atomicAdd(&bcnt[i], h[i]);
}

__global__ __launch_bounds__(256) void scan196_kernel(const int* __restrict__ bcnt,
                                                      int* __restrict__ boff) {
  __shared__ int s[256];
  const int tid = threadIdx.x;
  int v = (tid < NBK) ? bcnt[tid] : 0;
  s[tid] = v;
  __syncthreads();
  for (int off = 1; off < 256; off <<= 1) {
    int u = (tid >= off) ? s[tid - off] : 0;
    __syncthreads();
    s[tid] += u;
    __syncthreads();
  }
  if (tid <= NBK) boff[tid] = (tid == 0) ? 0 : s[tid - 1];
}

__global__ __launch_bounds__(256) void bucket_scatter_kernel(
    const int* __restrict__ row, const int* __restrict__ col,
    const int* __restrict__ boff, int* __restrict__ bfill,
    unsigned int* __restrict__ ebuf) {
  __shared__ int h[NBK], gst[NBK], h2[NBK];
  const int tid = threadIdx.x;
  for (int i = tid; i < NBK; i += 256) { h[i] = 0; h2[i] = 0; }
  __syncthreads();
  const int base = blockIdx.x * CHUNK;
  for (int i = tid; i < CHUNK; i += 256) atomicAdd(&h[col[base + i] >> 8], 1);
  __syncthreads();
  for (int i = tid; i < NBK; i += 256) gst[i] = h[i] ? atomicAdd(&bfill[i], h[i]) : 0;
  __syncthreads();
  for (int i = tid; i < CHUNK; i += 256) {
    int c = col[base + i];
    int b = c >> 8;
    int r = atomicAdd(&h2[b], 1);
    unsigned int packed = ((unsigned int)row[base + i] << 8) | (unsigned int)(c & 255);
    ebuf[boff[b] + gst[b] + r] = packed;
  }
}

__global__ __launch_bounds__(256) void bucket_build_kernel(
    const unsigned int* __restrict__ ebuf, const int* __restrict__ boff,
    int* __restrict__ row_ptr, float* __restrict__ dis, int* __restrict__ csr, int n) {
  __shared__ int cnt[256], c2[256], lbase[256], wsum[4];
  const int tid = threadIdx.x;
  const int b = blockIdx.x;
  const int s0 = boff[b], s1 = boff[b + 1];
  cnt[tid] = 0;
  c2[tid] = 0;
  __syncthreads();
  for (int i = s0 + tid; i < s1; i += 256) atomicAdd(&cnt[ebuf[i] & 255], 1);
  __syncthreads();

  const int lane = tid & 63, w = tid >> 6;
  int c = cnt[tid];
  int inc = c;
#pragma unroll
  for (int off = 1; off < 64; off <<= 1) {
    int u = __shfl_up(inc, off);
    if (lane >= off) inc += u;
  }
  if (lane == 63) wsum[w] = inc;
  __syncthreads();
  int wo = 0;
  for (int i = 0; i < w; ++i) wo += wsum[i];
  const int excl = wo + inc - c;

  const int node = b * 256 + tid;
  if (node <= n) row_ptr[node] = s0 + excl;
  if (node < n) dis[node] = rsqrtf((float)(c + 1));
  lbase[tid] = s0 + excl;
  __syncthreads();

  for (int i = s0 + tid; i < s1; i += 256) {
    unsigned int p = ebuf[i];
    int dl = p & 255;
    int r = atomicAdd(&c2[dl], 1);
    csr[lbase[dl] + r] = (int)(p >> 8);
  }
}

// ---------------- W prep: transpose + split f32 -> bf16 hi/lo ----------------

__global__ __launch_bounds__(256) void wprep_kernel(
    const float* __restrict__ W1, const float* __restrict__ W2,
    unsigned short* __restrict__ wt1h, unsigned short* __restrict__ wt1l,
    unsigned short* __restrict__ wt2h, unsigned short* __restrict__ wt2l) {
  int idx = blockIdx.x * 256 + threadIdx.x;  // 0..24575
  if (idx < 16384) {
    int c = idx >> 7, k = idx & 127;
    float w = W1[k * 128 + c];
    unsigned short h = f2bf(w);
    wt1h[idx] = h;
    wt1l[idx] = f2bf(w - bfval(h));
  } else if (idx < 24576) {
    int i2 = idx - 16384;
    int c = i2 >> 7, k = i2 & 127;
    float w = W2[k * 64 + c];
    unsigned short h = f2bf(w);
    wt2h[i2] = h;
    wt2l[i2] = f2bf(w - bfval(h));
  }
}

// ---------------- MFMA GEMM (R9-proven template + LDS-coalesced epilogue) ----------------
// out[r][c] = dis[r] * sum_{k<128} A[r][k] * Wt[c][k]
// gemm1: BM=64,  NCOLS=128 -> 4 waves 2x2 (32x64/wave), grid 782
// gemm2: BM=128, NCOLS=64  -> 4 waves 4x1 (32x64/wave), grid 391
// Epilogue: acc -> LDS tile (pitch NCOLS+8 bf16 / NCOLS+4 f32; 272B rows, 16B-aligned)
// -> coalesced dwordx4 global stores. Fixes the 3.5x write amplification seen in R11
// counters (partial 2-4B lane stores dirtying 64B lines).

template <int BM, int NCOLS, bool SPLITA, bool OUTBF16>
__global__ __launch_bounds__(256) void gemm_mfma_kernel(
    const void* __restrict__ Av, const unsigned short* __restrict__ Bth,
    const unsigned short* __restrict__ Btl, const float* __restrict__ dis,
    void* __restrict__ outv, int M) {
  constexpr int WCOL = NCOLS / 64;
  constexpr int WROW = 4 / WCOL;
  constexpr int RG = BM / (WROW * 16);
  constexpr int P = 40;
  constexpr int STAGE_SH = BM * P * (SPLITA ? 2 : 1) + NCOLS * P * 2;
  constexpr int EPI_PITCH = OUTBF16 ? (NCOLS + 8) : (NCOLS + 4);      // elems
  constexpr int EPI_SH = OUTBF16 ? BM * EPI_PITCH : BM * EPI_PITCH * 2;  // shorts
  constexpr int SMEM_SH = STAGE_SH > EPI_SH ? STAGE_SH : EPI_SH;

  __shared__ __align__(16) unsigned short smem[SMEM_SH];
  unsigned short* Ahp = smem;
  unsigned short* Alp = smem + BM * P;  // valid only if SPLITA
  unsigned short* Bhp = smem + BM * P * (SPLITA ? 2 : 1);
  unsigned short* Blp = Bhp + NCOLS * P;

  const int t = threadIdx.x;
  const int lane = t & 63;
  const int l15 = lane & 15;
  const int lg = lane >> 4;
  const int wv = t >> 6;
  const int wr = wv % WROW;
  const int wc = wv / WROW;
  const int rb = blockIdx.x * BM;

  f4v acc[RG][4];
#pragma unroll
  for (int i = 0; i < RG; ++i)
#pragma unroll
    for (int j = 0; j < 4; ++j) acc[i][j] = (f4v){0.f, 0.f, 0.f, 0.f};

  for (int kt = 0; kt < 4; ++kt) {
    if (kt) __syncthreads();
    // stage B tile [NCOLS][32] hi+lo
#pragma unroll
    for (int f = t; f < NCOLS * 4; f += 256) {
      int c = f >> 2, kq = f & 3;
      *reinterpret_cast<int4*>(&Bhp[c * P + kq * 8]) =
          *reinterpret_cast<const int4*>(&Bth[c * 128 + kt * 32 + kq * 8]);
      *reinterpret_cast<int4*>(&Blp[c * P + kq * 8]) =
          *reinterpret_cast<const int4*>(&Btl[c * 128 + kt * 32 + kq * 8]);
    }
    // stage A tile [BM][32]
    if constexpr (SPLITA) {
      const float* A = (const float*)Av;
#pragma unroll
      for (int j = 0; j < BM * 8 / 256; ++j) {
        int f = t + j * 256;
        int r = f >> 3, kq = f & 7;
        float4 v = make_float4(0.f, 0.f, 0.f, 0.f);
        if (rb + r < M)
          v = *reinterpret_cast<const float4*>(&A[(size_t)(rb + r) * 128 + kt * 32 + kq * 4]);
        ushort4 hv, lv;
        hv.x = f2bf(v.x); hv.y = f2bf(v.y); hv.z = f2bf(v.z); hv.w = f2bf(v.w);
        lv.x = f2bf(v.x - bfval(hv.x)); lv.y = f2bf(v.y - bfval(hv.y));
        lv.z = f2bf(v.z - bfval(hv.z)); lv.w = f2bf(v.w - bfval(hv.w));
        *reinterpret_cast<ushort4*>(&Ahp[r * P + kq * 4]) = hv;
        *reinterpret_cast<ushort4*>(&Alp[r * P + kq * 4]) = lv;
      }
    } else {
      const unsigned short* A = (const unsigned short*)Av;
#pragma unroll
      for (int j = 0; j < BM * 4 / 256; ++j) {
        int f = t + j * 256;
        int r = f >> 2, kq = f & 3;
        int4 v = {0, 0, 0, 0};
        if (rb + r < M)
          v = *reinterpret_cast<const int4*>(&A[(size_t)(rb + r) * 128 + kt * 32 + kq * 8]);
        *reinterpret_cast<int4*>(&Ahp[r * P + kq * 8]) = v;
      }
    }
    __syncthreads();

    s8v afh[RG], afl[RG];
#pragma unroll
    for (int rg = 0; rg < RG; ++rg) {
      afh[rg] = *reinterpret_cast<const s8v*>(&Ahp[(wr * (RG * 16) + rg * 16 + l15) * P + lg * 8]);
      if constexpr (SPLITA)
        afl[rg] = *reinterpret_cast<const s8v*>(&Alp[(wr * (RG * 16) + rg * 16 + l15) * P + lg * 8]);
    }
#pragma unroll
    for (int cg = 0; cg < 4; ++cg) {
      s8v bh = *reinterpret_cast<const s8v*>(&Bhp[(wc * 64 + cg * 16 + l15) * P + lg * 8]);
      s8v bl = *reinterpret_cast<const s8v*>(&Blp[(wc * 64 + cg * 16 + l15) * P + lg * 8]);
#pragma unroll
      for (int rg = 0; rg < RG; ++rg) {
        acc[rg][cg] = __builtin_amdgcn_mfma_f32_16x16x32_bf16(afh[rg], bh, acc[rg][cg], 0, 0, 0);
        acc[rg][cg] = __builtin_amdgcn_mfma_f32_16x16x32_bf16(afh[rg], bl, acc[rg][cg], 0, 0, 0);
        if constexpr (SPLITA)
          acc[rg][cg] = __builtin_amdgcn_mfma_f32_16x16x32_bf16(afl[rg], bh, acc[rg][cg], 0, 0, 0);
      }
    }
  }

  // ---- epilogue: scale, stage to LDS, coalesced store ----
  float dv[RG][4];
#pragma unroll
  for (int rg = 0; rg < RG; ++rg)
#pragma unroll
    for (int g = 0; g < 4; ++g) {
      int r = rb + wr * (RG * 16) + rg * 16 + lg * 4 + g;
      dv[rg][g] = (r < M) ? dis[r] : 0.f;
    }

  __syncthreads();  // all waves done with MFMA LDS reads; smem reusable

#pragma unroll
  for (int rg = 0; rg < RG; ++rg)
#pragma unroll
    for (int cg = 0; cg < 4; ++cg) {
      int colc = wc * 64 + cg * 16 + l15;
#pragma unroll
      for (int g = 0; g < 4; ++g) {
        int r = wr * (RG * 16) + rg * 16 + lg * 4 + g;  // block-local row
        float o = acc[rg][cg][g] * dv[rg][g];
        if constexpr (OUTBF16)
          smem[r * EPI_PITCH + colc] = f2bf(o);
        else
          reinterpret_cast<float*>(smem)[r * EPI_PITCH + colc] = o;
      }
    }
  __syncthreads();

  constexpr int CHR = OUTBF16 ? (NCOLS / 8) : (NCOLS / 4);  // 16B chunks per row
#pragma unroll
  for (int it = 0; it < BM * CHR / 256; ++it) {
    int ch = t + it * 256;
    int r = ch / CHR, cc = ch % CHR;
    if (rb + r < M) {
      if constexpr (OUTBF16) {
        int4 v = *reinterpret_cast<const int4*>(&smem[r * EPI_PITCH + cc * 8]);
        *reinterpret_cast<int4*>(&((unsigned short*)outv)[(size_t)(rb + r) * NCOLS + cc * 8]) = v;
      } else {
        int4 v = *reinterpret_cast<const int4*>(&reinterpret_cast<float*>(smem)[r * EPI_PITCH + cc * 4]);
        *reinterpret_cast<int4*>(&((float*)outv)[(size_t)(rb + r) * NCOLS + cc * 4]) = v;
      }
    }
  }
}

// ---------------- Aggregation (unroll 8, independent accumulators) ----------------

__global__ __launch_bounds__(256) void agg_bf16_kernel(
    const unsigned int* __restrict__ H, const int* __restrict__ row_ptr,
    const int* __restrict__ csr, const float* __restrict__ dis,
    const float* __restrict__ bias, unsigned int* __restrict__ Z, int n) {
  const int lane = threadIdx.x & 63;
  const int node = blockIdx.x * 4 + (threadIdx.x >> 6);
  if (node >= n) return;

  float2 a[8];
  a[0] = bfpair(H[(size_t)node * 64 + lane]);  // self-loop
#pragma unroll
  for (int i = 1; i < 8; ++i) a[i] = make_float2(0.f, 0.f);

  const int s0 = row_ptr[node], s1 = row_ptr[node + 1];
  for (int e = s0; e < s1; e += 64) {
    int m = s1 - e;
    if (m > 64) m = 64;
    int idx = 0;
    if (lane < m) idx = csr[e + lane];
    int j = 0;
    for (; j + 8 <= m; j += 8) {
      int i0 = __shfl(idx, j),     i1 = __shfl(idx, j + 1);
      int i2 = __shfl(idx, j + 2), i3 = __shfl(idx, j + 3);
      int i4 = __shfl(idx, j + 4), i5 = __shfl(idx, j + 5);
      int i6 = __shfl(idx, j + 6), i7 = __shfl(idx, j + 7);
      float2 v0 = bfpair(H[(size_t)i0 * 64 + lane]);
      float2 v1 = bfpair(H[(size_t)i1 * 64 + lane]);
      float2 v2 = bfpair(H[(size_t)i2 * 64 + lane]);
      float2 v3 = bfpair(H[(size_t)i3 * 64 + lane]);
      float2 v4 = bfpair(H[(size_t)i4 * 64 + lane]);
      float2 v5 = bfpair(H[(size_t)i5 * 64 + lane]);
      float2 v6 = bfpair(H[(size_t)i6 * 64 + lane]);
      float2 v7 = bfpair(H[(size_t)i7 * 64 + lane]);
      a[0].x += v0.x; a[0].y += v0.y;  a[1].x += v1.x; a[1].y += v1.y;
      a[2].x += v2.x; a[2].y += v2.y;  a[3].x += v3.x; a[3].y += v3.y;
      a[4].x += v4.x; a[4].y += v4.y;  a[5].x += v5.x; a[5].y += v5.y;
      a[6].x += v6.x; a[6].y += v6.y;  a[7].x += v7.x; a[7].y += v7.y;
    }
    for (; j + 4 <= m; j += 4) {
      int i0 = __shfl(idx, j),     i1 = __shfl(idx, j + 1);
      int i2 = __shfl(idx, j + 2), i3 = __shfl(idx, j + 3);
      float2 v0 = bfpair(H[(size_t)i0 * 64 + lane]);
      float2 v1 = bfpair(H[(size_t)i1 * 64 + lane]);
      float2 v2 = bfpair(H[(size_t)i2 * 64 + lane]);
      float2 v3 = bfpair(H[(size_t)i3 * 64 + lane]);
      a[0].x += v0.x; a[0].y += v0.y;  a[1].x += v1.x; a[1].y += v1.y;
      a[2].x += v2.x; a[2].y += v2.y;  a[3].x += v3.x; a[3].y += v3.y;
    }
    for (; j < m; ++j) {
      float2 v = bfpair(H[(size_t)__shfl(idx, j) * 64 + lane]);
      a[0].x += v.x; a[0].y += v.y;
    }
  }
  const float d = dis[node];
  float2 b = *reinterpret_cast<const float2*>(&bias[lane * 2]);
  float sx = ((a[0].x + a[1].x) + (a[2].x + a[3].x)) + ((a[4].x + a[5].x) + (a[6].x + a[7].x));
  float sy = ((a[0].y + a[1].y) + (a[2].y + a[3].y)) + ((a[4].y + a[5].y) + (a[6].y + a[7].y));
  float ox = fmaxf(sx * d + b.x, 0.f);
  float oy = fmaxf(sy * d + b.y, 0.f);
  Z[(size_t)node * 64 + lane] = (unsigned int)f2bf(ox) | ((unsigned int)f2bf(oy) << 16);
}

__global__ __launch_bounds__(256) void agg_f32_kernel(
    const float* __restrict__ Hs, const int* __restrict__ row_ptr,
    const int* __restrict__ csr, const float* __restrict__ dis,
    const float* __restrict__ bias, float* __restrict__ out, int n) {
  const int lane = threadIdx.x & 63;
  const int node = blockIdx.x * 4 + (threadIdx.x >> 6);
  if (node >= n) return;

  float a[8];
  a[0] = Hs[(size_t)node * 64 + lane];  // self-loop
#pragma unroll
  for (int i = 1; i < 8; ++i) a[i] = 0.f;

  const int s0 = row_ptr[node], s1 = row_ptr[node + 1];
  for (int e = s0; e < s1; e += 64) {
    int m = s1 - e;
    if (m > 64) m = 64;
    int idx = 0;
    if (lane < m) idx = csr[e + lane];
    int j = 0;
    for (; j + 8 <= m; j += 8) {
      int i0 = __shfl(idx, j),     i1 = __shfl(idx, j + 1);
      int i2 = __shfl(idx, j + 2), i3 = __shfl(idx, j + 3);
      int i4 = __shfl(idx, j + 4), i5 = __shfl(idx, j + 5);
      int i6 = __shfl(idx, j + 6), i7 = __shfl(idx, j + 7);
      float v0 = Hs[(size_t)i0 * 64 + lane];
      float v1 = Hs[(size_t)i1 * 64 + lane];
      float v2 = Hs[(size_t)i2 * 64 + lane];
      float v3 = Hs[(size_t)i3 * 64 + lane];
      float v4 = Hs[(size_t)i4 * 64 + lane];
      float v5 = Hs[(size_t)i5 * 64 + lane];
      float v6 = Hs[(size_t)i6 * 64 + lane];
      float v7 = Hs[(size_t)i7 * 64 + lane];
      a[0] += v0; a[1] += v1; a[2] += v2; a[3] += v3;
      a[4] += v4; a[5] += v5; a[6] += v6; a[7] += v7;
    }
    for (; j + 4 <= m; j += 4) {
      int i0 = __shfl(idx, j),     i1 = __shfl(idx, j + 1);
      int i2 = __shfl(idx, j + 2), i3 = __shfl(idx, j + 3);
      float v0 = Hs[(size_t)i0 * 64 + lane];
      float v1 = Hs[(size_t)i1 * 64 + lane];
      float v2 = Hs[(size_t)i2 * 64 + lane];
      float v3 = Hs[(size_t)i3 * 64 + lane];
      a[0] += v0; a[1] += v1; a[2] += v2; a[3] += v3;
    }
    for (; j < m; ++j) a[0] += Hs[(size_t)__shfl(idx, j) * 64 + lane];
  }
  float s = ((a[0] + a[1]) + (a[2] + a[3])) + ((a[4] + a[5]) + (a[6] + a[7]));
  out[(size_t)node * 64 + lane] = s * dis[node] + bias[lane];
}

// ---------------- launch ----------------

extern "C" void kernel_launch(void* const* d_in, const int* in_sizes, int n_in,
                              void* d_out, int out_size, void* d_ws, size_t ws_size,
                              hipStream_t stream) {
  const float* x  = (const float*)d_in[0];
  const int*   ei = (const int*)d_in[1];
  const float* W1 = (const float*)d_in[2];
  const float* b1 = (const float*)d_in[3];
  const float* W2 = (const float*)d_in[4];
  const float* b2 = (const float*)d_in[5];
  float* out = (float*)d_out;

  const int* row = ei;        // source nodes
  const int* col = ei + NE;   // destination nodes

  char* ws = (char*)d_ws;
  size_t off = 0;
  auto alloc = [&](size_t bytes) -> void* {
    off = (off + 255) & ~(size_t)255;
    void* p = ws + off;
    off += bytes;
    return p;
  };

  int* bcnt    = (int*)alloc((size_t)2 * NBK * sizeof(int));  // bcnt | bfill
  int* bfill   = bcnt + NBK;
  int* boff    = (int*)alloc((size_t)(NBK + 1) * sizeof(int));
  unsigned int* ebuf = (unsigned int*)alloc((size_t)NE * sizeof(unsigned int));
  int* row_ptr = (int*)alloc((size_t)(NN + 1) * sizeof(int));
  int* csr     = (int*)alloc((size_t)NE * sizeof(int));
  float* dis   = (float*)alloc((size_t)NN * sizeof(float));
  unsigned short* wt1h = (unsigned short*)alloc((size_t)(2 * 128 * 128 + 2 * 64 * 128) * 2);
  unsigned short* wt1l = wt1h + 128 * 128;
  unsigned short* wt2h = wt1l + 128 * 128;
  unsigned short* wt2l = wt2h + 64 * 128;
  // HT region: bf16 [NN][128] for layer-1 GEMM out, then f32 [NN][64] for layer-2
  unsigned short* HT16 = (unsigned short*)alloc((size_t)NN * 128 * 2);
  float* HT32 = (float*)HT16;
  unsigned int* HTu = (unsigned int*)HT16;
  unsigned short* Z1 = (unsigned short*)alloc((size_t)NN * 128 * 2);
  unsigned int* Z1u = (unsigned int*)Z1;

  hipMemsetAsync(bcnt, 0, (size_t)2 * NBK * sizeof(int), stream);
  wprep_kernel<<<96, 256, 0, stream>>>(W1, W2, wt1h, wt1l, wt2h, wt2l);
  bucket_count_kernel<<<NE / CHUNK, 256, 0, stream>>>(col, bcnt);
  scan196_kernel<<<1, 256, 0, stream>>>(bcnt, boff);
  bucket_scatter_kernel<<<NE / CHUNK, 256, 0, stream>>>(row, col, boff, bfill, ebuf);
  bucket_build_kernel<<<NBK, 256, 0, stream>>>(ebuf, boff, row_ptr, dis, csr, NN);

  const int ga = (NN + 3) / 4;

  // Layer 1: HT16 = bf16( dis .* (X @ W1) )  [NN][128], BM=64 -> 782 blocks
  gemm_mfma_kernel<64, 128, true, true><<<(NN + 63) / 64, 256, 0, stream>>>(
      x, wt1h, wt1l, dis, HT16, NN);
  agg_bf16_kernel<<<ga, 256, 0, stream>>>(HTu, row_ptr, csr, dis, b1, Z1u, NN);

  // Layer 2: HT32 = dis .* (Z1 @ W2)  [NN][64], BM=128 -> 391 blocks
  gemm_mfma_kernel<128, 64, false, false><<<(NN + 127) / 128, 256, 0, stream>>>(
      Z1, wt2h, wt2l, dis, HT32, NN);
  agg_f32_kernel<<<ga, 256, 0, stream>>>(HT32, row_ptr, csr, dis, b2, out, NN);
}

// Round 14
// 123.758 us; speedup vs baseline: 1.2515x; 1.0163x over previous
//
#include <hip/hip_runtime.h>

#define NN 50000
#define NE 640000
#define NBK 196      // buckets of 256 nodes
#define CHUNK 2560   // edges per block in bucket passes: NE/CHUNK = 250

typedef __attribute__((ext_vector_type(8))) short s8v;
typedef __attribute__((ext_vector_type(4))) float f4v;

__device__ __forceinline__ unsigned short f2bf(float x) {  // RNE f32->bf16
  unsigned int u = __float_as_uint(x);
  return (unsigned short)((u + 0x7fffu + ((u >> 16) & 1u)) >> 16);
}
__device__ __forceinline__ float bfval(unsigned short h) {
  return __uint_as_float((unsigned int)h << 16);
}
__device__ __forceinline__ float2 bfpair(unsigned int u) {
  float2 r;
  r.x = __uint_as_float((u & 0xffffu) << 16);
  r.y = __uint_as_float(u & 0xffff0000u);
  return r;
}

// async global->LDS, 16B per lane; LDS dest = wave-uniform base + lane*16
__device__ __forceinline__ void gload_lds16(const void* g, void* l) {
  __builtin_amdgcn_global_load_lds(
      (const __attribute__((address_space(1))) void*)g,
      (__attribute__((address_space(3))) void*)l, 16, 0, 0);
}

// ---------------- Bucketed CSR (dest-keyed) build ----------------

__global__ __launch_bounds__(256) void bucket_count_kernel(const int* __restrict__ col,
                                                           int* __restrict__ bcnt) {
  __shared__ int h[NBK];
  const int tid = threadIdx.x;
  for (int i = tid; i < NBK; i += 256) h[i] = 0;
  __syncthreads();
  const int base = blockIdx.x * CHUNK;
  for (int i = tid; i < CHUNK; i += 256) atomicAdd(&h[col[base + i] >> 8], 1);
  __syncthreads();
  for (int i = tid; i < NBK; i += 256)
    if (h[i]) atomicAdd(&bcnt[i], h[i]);
}

__global__ __launch_bounds__(256) void scan196_kernel(const int* __restrict__ bcnt,
                                                      int* __restrict__ boff) {
  __shared__ int s[256];
  const int tid = threadIdx.x;
  int v = (tid < NBK) ? bcnt[tid] : 0;
  s[tid] = v;
  __syncthreads();
  for (int off = 1; off < 256; off <<= 1) {
    int u = (tid >= off) ? s[tid - off] : 0;
    __syncthreads();
    s[tid] += u;
    __syncthreads();
  }
  if (tid <= NBK) boff[tid] = (tid == 0) ? 0 : s[tid - 1];
}

__global__ __launch_bounds__(256) void bucket_scatter_kernel(
    const int* __restrict__ row, const int* __restrict__ col,
    const int* __restrict__ boff, int* __restrict__ bfill,
    unsigned int* __restrict__ ebuf) {
  __shared__ int h[NBK], gst[NBK], h2[NBK];
  const int tid = threadIdx.x;
  for (int i = tid; i < NBK; i += 256) { h[i] = 0; h2[i] = 0; }
  __syncthreads();
  const int base = blockIdx.x * CHUNK;
  for (int i = tid; i < CHUNK; i += 256) atomicAdd(&h[col[base + i] >> 8], 1);
  __syncthreads();
  for (int i = tid; i < NBK; i += 256) gst[i] = h[i] ? atomicAdd(&bfill[i], h[i]) : 0;
  __syncthreads();
  for (int i = tid; i < CHUNK; i += 256) {
    int c = col[base + i];
    int b = c >> 8;
    int r = atomicAdd(&h2[b], 1);
    unsigned int packed = ((unsigned int)row[base + i] << 8) | (unsigned int)(c & 255);
    ebuf[boff[b] + gst[b] + r] = packed;
  }
}

__global__ __launch_bounds__(256) void bucket_build_kernel(
    const unsigned int* __restrict__ ebuf, const int* __restrict__ boff,
    int* __restrict__ row_ptr, float* __restrict__ dis, int* __restrict__ csr, int n) {
  __shared__ int cnt[256], c2[256], lbase[256], wsum[4];
  const int tid = threadIdx.x;
  const int b = blockIdx.x;
  const int s0 = boff[b], s1 = boff[b + 1];
  cnt[tid] = 0;
  c2[tid] = 0;
  __syncthreads();
  for (int i = s0 + tid; i < s1; i += 256) atomicAdd(&cnt[ebuf[i] & 255], 1);
  __syncthreads();

  const int lane = tid & 63, w = tid >> 6;
  int c = cnt[tid];
  int inc = c;
#pragma unroll
  for (int off = 1; off < 64; off <<= 1) {
    int u = __shfl_up(inc, off);
    if (lane >= off) inc += u;
  }
  if (lane == 63) wsum[w] = inc;
  __syncthreads();
  int wo = 0;
  for (int i = 0; i < w; ++i) wo += wsum[i];
  const int excl = wo + inc - c;

  const int node = b * 256 + tid;
  if (node <= n) row_ptr[node] = s0 + excl;
  if (node < n) dis[node] = rsqrtf((float)(c + 1));
  lbase[tid] = s0 + excl;
  __syncthreads();

  for (int i = s0 + tid; i < s1; i += 256) {
    unsigned int p = ebuf[i];
    int dl = p & 255;
    int r = atomicAdd(&c2[dl], 1);
    csr[lbase[dl] + r] = (int)(p >> 8);
  }
}

// ---------------- W prep: transpose + split f32 -> bf16 hi/lo ----------------

__global__ __launch_bounds__(256) void wprep_kernel(
    const float* __restrict__ W1, const float* __restrict__ W2,
    unsigned short* __restrict__ wt1h, unsigned short* __restrict__ wt1l,
    unsigned short* __restrict__ wt2h, unsigned short* __restrict__ wt2l) {
  int idx = blockIdx.x * 256 + threadIdx.x;  // 0..24575
  if (idx < 16384) {
    int c = idx >> 7, k = idx & 127;
    float w = W1[k * 128 + c];
    unsigned short h = f2bf(w);
    wt1h[idx] = h;
    wt1l[idx] = f2bf(w - bfval(h));
  } else if (idx < 24576) {
    int i2 = idx - 16384;
    int c = i2 >> 7, k = i2 & 127;
    float w = W2[k * 64 + c];
    unsigned short h = f2bf(w);
    wt2h[i2] = h;
    wt2l[i2] = f2bf(w - bfval(h));
  }
}

// ---------------- MFMA GEMM: global_load_lds staging (m97 pattern) ----------------
// out[r][c] = dis[r] * sum_{k<128} A[r][k] * Wt[c][k]
// gemm1: BM=64,  NCOLS=128, A f32 in LDS (split to hi/lo at frag-read; VALU co-issues w/ MFMA)
// gemm2: BM=128, NCOLS=64,  A bf16 in LDS
// Staging = pure __builtin_amdgcn_global_load_lds width-16 (guide Common-mistake #1 fix):
// linear LDS tiles, per-lane clamped global src, wave-uniform LDS base.
// K-loop keeps the R13-proven 2-barrier structure; LDS-coalesced epilogue kept.

template <int BM, int NCOLS, bool AF32, bool OUTBF16>
__global__ __launch_bounds__(256) void gemm_mfma_kernel(
    const void* __restrict__ Av, const unsigned short* __restrict__ Bth,
    const unsigned short* __restrict__ Btl, const float* __restrict__ dis,
    void* __restrict__ outv, int M) {
  constexpr int WCOL = NCOLS / 64;
  constexpr int WROW = 4 / WCOL;
  constexpr int RG = BM / (WROW * 16);
  constexpr int A_BYTES = BM * 32 * (AF32 ? 4 : 2);   // A tile [BM][32]
  constexpr int B_BYTES = NCOLS * 32 * 2;             // per table [NCOLS][32] bf16
  constexpr int STAGE_BYTES = A_BYTES + 2 * B_BYTES;
  constexpr int EPI_PITCH = OUTBF16 ? (NCOLS + 8) : (NCOLS + 4);
  constexpr int EPI_BYTES = BM * EPI_PITCH * (OUTBF16 ? 2 : 4);
  constexpr int SMEM_BYTES = STAGE_BYTES > EPI_BYTES ? STAGE_BYTES : EPI_BYTES;

  __shared__ __align__(16) unsigned char smem[SMEM_BYTES];

  const int t = threadIdx.x;
  const int lane = t & 63;
  const int l15 = lane & 15;
  const int lg = lane >> 4;
  const int wv = t >> 6;
  const int wr = wv % WROW;
  const int wc = wv / WROW;
  const int rb = blockIdx.x * BM;

  f4v acc[RG][4];
#pragma unroll
  for (int i = 0; i < RG; ++i)
#pragma unroll
    for (int j = 0; j < 4; ++j) acc[i][j] = (f4v){0.f, 0.f, 0.f, 0.f};

  for (int kt = 0; kt < 4; ++kt) {
    if (kt) __syncthreads();  // prev compute's ds_reads done before overwrite

    // ---- stage A tile via global_load_lds ----
    if constexpr (AF32) {
      // [BM][32] f32, 128B rows; 1KB/call = 8 rows; BM*128/1024 calls
      constexpr int CPW = (BM * 128 / 1024) / 4;  // calls per wave
#pragma unroll
      for (int j = 0; j < CPW; ++j) {
        int callr = (wv * CPW + j) * 8;
        int gr = min(rb + callr + (lane >> 3), M - 1);
        const float* gp = (const float*)Av + (size_t)gr * 128 + kt * 32 + (lane & 7) * 4;
        gload_lds16(gp, smem + callr * 128);
      }
    } else {
      // [BM][32] bf16, 64B rows; 1KB/call = 16 rows
      constexpr int CPW = (BM * 64 / 1024) / 4;
#pragma unroll
      for (int j = 0; j < CPW; ++j) {
        int callr = (wv * CPW + j) * 16;
        int gr = min(rb + callr + (lane >> 2), M - 1);
        const unsigned short* gp =
            (const unsigned short*)Av + (size_t)gr * 128 + kt * 32 + (lane & 3) * 8;
        gload_lds16(gp, smem + callr * 64);
      }
    }
    // ---- stage B tiles (hi, lo) ----
    {
      constexpr int CPW = (NCOLS * 64 / 1024) / 4;  // 2 (gemm1) or 1 (gemm2)
#pragma unroll
      for (int j = 0; j < CPW; ++j) {
        int callr = (wv * CPW + j) * 16;
        int r = callr + (lane >> 2);
        size_t goff = (size_t)r * 128 + kt * 32 + (lane & 3) * 8;
        gload_lds16(Bth + goff, smem + A_BYTES + callr * 64);
        gload_lds16(Btl + goff, smem + A_BYTES + B_BYTES + callr * 64);
      }
    }
    __syncthreads();  // implicit vmcnt(0) drain -> tiles landed

    // ---- fragments + MFMA ----
    s8v afh[RG], afl[RG];
#pragma unroll
    for (int rg = 0; rg < RG; ++rg) {
      int row = wr * (RG * 16) + rg * 16 + l15;
      if constexpr (AF32) {
        const float* ap = (const float*)smem + row * 32 + lg * 8;
        float4 x0 = *reinterpret_cast<const float4*>(ap);
        float4 x1 = *reinterpret_cast<const float4*>(ap + 4);
        float f[8] = {x0.x, x0.y, x0.z, x0.w, x1.x, x1.y, x1.z, x1.w};
#pragma unroll
        for (int q = 0; q < 8; ++q) {
          unsigned short hq = f2bf(f[q]);
          afh[rg][q] = (short)hq;
          afl[rg][q] = (short)f2bf(f[q] - bfval(hq));
        }
      } else {
        afh[rg] = *reinterpret_cast<const s8v*>((const unsigned short*)smem + row * 32 + lg * 8);
      }
    }
#pragma unroll
    for (int cg = 0; cg < 4; ++cg) {
      int colr = wc * 64 + cg * 16 + l15;
      s8v bh = *reinterpret_cast<const s8v*>(
          (const unsigned short*)(smem + A_BYTES) + colr * 32 + lg * 8);
      s8v bl = *reinterpret_cast<const s8v*>(
          (const unsigned short*)(smem + A_BYTES + B_BYTES) + colr * 32 + lg * 8);
#pragma unroll
      for (int rg = 0; rg < RG; ++rg) {
        acc[rg][cg] = __builtin_amdgcn_mfma_f32_16x16x32_bf16(afh[rg], bh, acc[rg][cg], 0, 0, 0);
        acc[rg][cg] = __builtin_amdgcn_mfma_f32_16x16x32_bf16(afh[rg], bl, acc[rg][cg], 0, 0, 0);
        if constexpr (AF32)
          acc[rg][cg] = __builtin_amdgcn_mfma_f32_16x16x32_bf16(afl[rg], bh, acc[rg][cg], 0, 0, 0);
      }
    }
  }

  // ---- epilogue: scale, stage to LDS, coalesced store (R13-proven) ----
  float dv[RG][4];
#pragma unroll
  for (int rg = 0; rg < RG; ++rg)
#pragma unroll
    for (int g = 0; g < 4; ++g) {
      int r = rb + wr * (RG * 16) + rg * 16 + lg * 4 + g;
      dv[rg][g] = (r < M) ? dis[r] : 0.f;
    }

  __syncthreads();  // all MFMA LDS reads done; smem reusable

#pragma unroll
  for (int rg = 0; rg < RG; ++rg)
#pragma unroll
    for (int cg = 0; cg < 4; ++cg) {
      int colc = wc * 64 + cg * 16 + l15;
#pragma unroll
      for (int g = 0; g < 4; ++g) {
        int r = wr * (RG * 16) + rg * 16 + lg * 4 + g;  // block-local row
        float o = acc[rg][cg][g] * dv[rg][g];
        if constexpr (OUTBF16)
          ((unsigned short*)smem)[r * EPI_PITCH + colc] = f2bf(o);
        else
          ((float*)smem)[r * EPI_PITCH + colc] = o;
      }
    }
  __syncthreads();

  constexpr int CHR = OUTBF16 ? (NCOLS / 8) : (NCOLS / 4);  // 16B chunks per row
#pragma unroll
  for (int it = 0; it < BM * CHR / 256; ++it) {
    int ch = t + it * 256;
    int r = ch / CHR, cc = ch % CHR;
    if (rb + r < M) {
      if constexpr (OUTBF16) {
        int4 v = *reinterpret_cast<const int4*>(&((unsigned short*)smem)[r * EPI_PITCH + cc * 8]);
        *reinterpret_cast<int4*>(&((unsigned short*)outv)[(size_t)(rb + r) * NCOLS + cc * 8]) = v;
      } else {
        int4 v = *reinterpret_cast<const int4*>(&((float*)smem)[r * EPI_PITCH + cc * 4]);
        *reinterpret_cast<int4*>(&((float*)outv)[(size_t)(rb + r) * NCOLS + cc * 4]) = v;
      }
    }
  }
}

// ---------------- Aggregation (unroll 8, independent accumulators) ----------------

__global__ __launch_bounds__(256) void agg_bf16_kernel(
    const unsigned int* __restrict__ H, const int* __restrict__ row_ptr,
    const int* __restrict__ csr, const float* __restrict__ dis,
    const float* __restrict__ bias, unsigned int* __restrict__ Z, int n) {
  const int lane = threadIdx.x & 63;
  const int node = blockIdx.x * 4 + (threadIdx.x >> 6);
  if (node >= n) return;

  float2 a[8];
  a[0] = bfpair(H[(size_t)node * 64 + lane]);  // self-loop
#pragma unroll
  for (int i = 1; i < 8; ++i) a[i] = make_float2(0.f, 0.f);

  const int s0 = row_ptr[node], s1 = row_ptr[node + 1];
  for (int e = s0; e < s1; e += 64) {
    int m = s1 - e;
    if (m > 64) m = 64;
    int idx = 0;
    if (lane < m) idx = csr[e + lane];
    int j = 0;
    for (; j + 8 <= m; j += 8) {
      int i0 = __shfl(idx, j),     i1 = __shfl(idx, j + 1);
      int i2 = __shfl(idx, j + 2), i3 = __shfl(idx, j + 3);
      int i4 = __shfl(idx, j + 4), i5 = __shfl(idx, j + 5);
      int i6 = __shfl(idx, j + 6), i7 = __shfl(idx, j + 7);
      float2 v0 = bfpair(H[(size_t)i0 * 64 + lane]);
      float2 v1 = bfpair(H[(size_t)i1 * 64 + lane]);
      float2 v2 = bfpair(H[(size_t)i2 * 64 + lane]);
      float2 v3 = bfpair(H[(size_t)i3 * 64 + lane]);
      float2 v4 = bfpair(H[(size_t)i4 * 64 + lane]);
      float2 v5 = bfpair(H[(size_t)i5 * 64 + lane]);
      float2 v6 = bfpair(H[(size_t)i6 * 64 + lane]);
      float2 v7 = bfpair(H[(size_t)i7 * 64 + lane]);
      a[0].x += v0.x; a[0].y += v0.y;  a[1].x += v1.x; a[1].y += v1.y;
      a[2].x += v2.x; a[2].y += v2.y;  a[3].x += v3.x; a[3].y += v3.y;
      a[4].x += v4.x; a[4].y += v4.y;  a[5].x += v5.x; a[5].y += v5.y;
      a[6].x += v6.x; a[6].y += v6.y;  a[7].x += v7.x; a[7].y += v7.y;
    }
    for (; j + 4 <= m; j += 4) {
      int i0 = __shfl(idx, j),     i1 = __shfl(idx, j + 1);
      int i2 = __shfl(idx, j + 2), i3 = __shfl(idx, j + 3);
      float2 v0 = bfpair(H[(size_t)i0 * 64 + lane]);
      float2 v1 = bfpair(H[(size_t)i1 * 64 + lane]);
      float2 v2 = bfpair(H[(size_t)i2 * 64 + lane]);
      float2 v3 = bfpair(H[(size_t)i3 * 64 + lane]);
      a[0].x += v0.x; a[0].y += v0.y;  a[1].x += v1.x; a[1].y += v1.y;
      a[2].x += v2.x; a[2].y += v2.y;  a[3].x += v3.x; a[3].y += v3.y;
    }
    for (; j < m; ++j) {
      float2 v = bfpair(H[(size_t)__shfl(idx, j) * 64 + lane]);
      a[0].x += v.x; a[0].y += v.y;
    }
  }
  const float d = dis[node];
  float2 b = *reinterpret_cast<const float2*>(&bias[lane * 2]);
  float sx = ((a[0].x + a[1].x) + (a[2].x + a[3].x)) + ((a[4].x + a[5].x) + (a[6].x + a[7].x));
  float sy = ((a[0].y + a[1].y) + (a[2].y + a[3].y)) + ((a[4].y + a[5].y) + (a[6].y + a[7].y));
  float ox = fmaxf(sx * d + b.x, 0.f);
  float oy = fmaxf(sy * d + b.y, 0.f);
  Z[(size_t)node * 64 + lane] = (unsigned int)f2bf(ox) | ((unsigned int)f2bf(oy) << 16);
}

__global__ __launch_bounds__(256) void agg_f32_kernel(
    const float* __restrict__ Hs, const int* __restrict__ row_ptr,
    const int* __restrict__ csr, const float* __restrict__ dis,
    const float* __restrict__ bias, float* __restrict__ out, int n) {
  const int lane = threadIdx.x & 63;
  const int node = blockIdx.x * 4 + (threadIdx.x >> 6);
  if (node >= n) return;

  float a[8];
  a[0] = Hs[(size_t)node * 64 + lane];  // self-loop
#pragma unroll
  for (int i = 1; i < 8; ++i) a[i] = 0.f;

  const int s0 = row_ptr[node], s1 = row_ptr[node + 1];
  for (int e = s0; e < s1; e += 64) {
    int m = s1 - e;
    if (m > 64) m = 64;
    int idx = 0;
    if (lane < m) idx = csr[e + lane];
    int j = 0;
    for (; j + 8 <= m; j += 8) {
      int i0 = __shfl(idx, j),     i1 = __shfl(idx, j + 1);
      int i2 = __shfl(idx, j + 2), i3 = __shfl(idx, j + 3);
      int i4 = __shfl(idx, j + 4), i5 = __shfl(idx, j + 5);
      int i6 = __shfl(idx, j + 6), i7 = __shfl(idx, j + 7);
      float v0 = Hs[(size_t)i0 * 64 + lane];
      float v1 = Hs[(size_t)i1 * 64 + lane];
      float v2 = Hs[(size_t)i2 * 64 + lane];
      float v3 = Hs[(size_t)i3 * 64 + lane];
      float v4 = Hs[(size_t)i4 * 64 + lane];
      float v5 = Hs[(size_t)i5 * 64 + lane];
      float v6 = Hs[(size_t)i6 * 64 + lane];
      float v7 = Hs[(size_t)i7 * 64 + lane];
      a[0] += v0; a[1] += v1; a[2] += v2; a[3] += v3;
      a[4] += v4; a[5] += v5; a[6] += v6; a[7] += v7;
    }
    for (; j + 4 <= m; j += 4) {
      int i0 = __shfl(idx, j),     i1 = __shfl(idx, j + 1);
      int i2 = __shfl(idx, j + 2), i3 = __shfl(idx, j + 3);
      float v0 = Hs[(size_t)i0 * 64 + lane];
      float v1 = Hs[(size_t)i1 * 64 + lane];
      float v2 = Hs[(size_t)i2 * 64 + lane];
      float v3 = Hs[(size_t)i3 * 64 + lane];
      a[0] += v0; a[1] += v1; a[2] += v2; a[3] += v3;
    }
    for (; j < m; ++j) a[0] += Hs[(size_t)__shfl(idx, j) * 64 + lane];
  }
  float s = ((a[0] + a[1]) + (a[2] + a[3])) + ((a[4] + a[5]) + (a[6] + a[7]));
  out[(size_t)node * 64 + lane] = s * dis[node] + bias[lane];
}

// ---------------- launch ----------------

extern "C" void kernel_launch(void* const* d_in, const int* in_sizes, int n_in,
                              void* d_out, int out_size, void* d_ws, size_t ws_size,
                              hipStream_t stream) {
  const float* x  = (const float*)d_in[0];
  const int*   ei = (const int*)d_in[1];
  const float* W1 = (const float*)d_in[2];
  const float* b1 = (const float*)d_in[3];
  const float* W2 = (const float*)d_in[4];
  const float* b2 = (const float*)d_in[5];
  float* out = (float*)d_out;

  const int* row = ei;        // source nodes
  const int* col = ei + NE;   // destination nodes

  char* ws = (char*)d_ws;
  size_t off = 0;
  auto alloc = [&](size_t bytes) -> void* {
    off = (off + 255) & ~(size_t)255;
    void* p = ws + off;
    off += bytes;
    return p;
  };

  int* bcnt    = (int*)alloc((size_t)2 * NBK * sizeof(int));  // bcnt | bfill
  int* bfill   = bcnt + NBK;
  int* boff    = (int*)alloc((size_t)(NBK + 1) * sizeof(int));
  unsigned int* ebuf = (unsigned int*)alloc((size_t)NE * sizeof(unsigned int));
  int* row_ptr = (int*)alloc((size_t)(NN + 1) * sizeof(int));
  int* csr     = (int*)alloc((size_t)NE * sizeof(int));
  float* dis   = (float*)alloc((size_t)NN * sizeof(float));
  unsigned short* wt1h = (unsigned short*)alloc((size_t)(2 * 128 * 128 + 2 * 64 * 128) * 2);
  unsigned short* wt1l = wt1h + 128 * 128;
  unsigned short* wt2h = wt1l + 128 * 128;
  unsigned short* wt2l = wt2h + 64 * 128;
  // HT region: bf16 [NN][128] for layer-1 GEMM out, then f32 [NN][64] for layer-2
  unsigned short* HT16 = (unsigned short*)alloc((size_t)NN * 128 * 2);
  float* HT32 = (float*)HT16;
  unsigned int* HTu = (unsigned int*)HT16;
  unsigned short* Z1 = (unsigned short*)alloc((size_t)NN * 128 * 2);
  unsigned int* Z1u = (unsigned int*)Z1;

  hipMemsetAsync(bcnt, 0, (size_t)2 * NBK * sizeof(int), stream);
  wprep_kernel<<<96, 256, 0, stream>>>(W1, W2, wt1h, wt1l, wt2h, wt2l);
  bucket_count_kernel<<<NE / CHUNK, 256, 0, stream>>>(col, bcnt);
  scan196_kernel<<<1, 256, 0, stream>>>(bcnt, boff);
  bucket_scatter_kernel<<<NE / CHUNK, 256, 0, stream>>>(row, col, boff, bfill, ebuf);
  bucket_build_kernel<<<NBK, 256, 0, stream>>>(ebuf, boff, row_ptr, dis, csr, NN);

  const int ga = (NN + 3) / 4;

  // Layer 1: HT16 = bf16( dis .* (X @ W1) )  [NN][128], BM=64 -> 782 blocks
  gemm_mfma_kernel<64, 128, true, true><<<(NN + 63) / 64, 256, 0, stream>>>(
      x, wt1h, wt1l, dis, HT16, NN);
  agg_bf16_kernel<<<ga, 256, 0, stream>>>(HTu, row_ptr, csr, dis, b1, Z1u, NN);

  // Layer 2: HT32 = dis .* (Z1 @ W2)  [NN][64], BM=128 -> 391 blocks
  gemm_mfma_kernel<128, 64, false, false><<<(NN + 127) / 128, 256, 0, stream>>>(
      Z1, wt2h, wt2l, dis, HT32, NN);
  agg_f32_kernel<<<ga, 256, 0, stream>>>(HT32, row_ptr, csr, dis, b2, out, NN);
}